// Round 1
// baseline (484.191 us; speedup 1.0000x reference)
//
#include <hip/hip_runtime.h>

#define NB  32
#define NTC 2048
#define NTQ 256
#define ND  256

// ---------------- ws layout (floats) ----------------
// q2     : [32][256]          @ 0        (8192)
// m      : [32][2048]         @ 8192     (65536)
// h_part : [32][16][256]      @ 73728    (131072)
// h      : [32][256]          @ 204800   (8192)
#define Q2_OFF 0
#define M_OFF  8192
#define HP_OFF 73728
#define H_OFF  204800

// K0: q2[b][q] = dot(query[b,q,:], w2)
__global__ __launch_bounds__(256) void k0_q2(const float* __restrict__ qry,
                                             const float* __restrict__ w,
                                             float* __restrict__ q2_ws) {
  int b = blockIdx.x;
  int wv = threadIdx.x >> 6;
  int lane = threadIdx.x & 63;
  float4 w2v = *(const float4*)(w + ND + lane * 4);
  const float* qb = qry + (size_t)b * NTQ * ND;
  for (int i = 0; i < 64; ++i) {
    int q = wv * 64 + i;
    float4 v = *(const float4*)(qb + (size_t)q * ND + lane * 4);
    float acc = v.x * w2v.x + v.y * w2v.y + v.z * w2v.z + v.w * w2v.w;
    #pragma unroll
    for (int s = 1; s < 64; s <<= 1) acc += __shfl_xor(acc, s);
    if (lane == 0) q2_ws[b * NTQ + q] = acc;
  }
}

// K1: per (b, 64-row tile): S = s1 + q2 + (C*w3)Q^T ; rowmax->m_ws ; P=softmax ;
//     U = P Q ; write G[...,256:512]=U, G[...,512:768]=C*U
__global__ __launch_bounds__(256) void k1_main(const float* __restrict__ ctx,
                                               const float* __restrict__ qry,
                                               const float* __restrict__ w,
                                               const float* __restrict__ q2_ws,
                                               float* __restrict__ m_ws,
                                               float* __restrict__ G) {
  __shared__ __align__(16) float sQ[NTQ * 68];   // query d-chunk [256][68]
  __shared__ __align__(16) float sC[64 * 68];    // context tile d-chunk [64][68]
  __shared__ __align__(16) float sP[64 * 260];   // P [64][260]

  int bx = blockIdx.x;
  int b  = bx >> 5;
  int t0 = (bx & 31) << 6;
  int tid = threadIdx.x;
  int tt = tid >> 4;    // row group: rows 4*tt .. 4*tt+3
  int tq = tid & 15;    // q ownership: q = tq + 16*j ; also d-col group in phase 2

  const float* w1 = w;
  const float* w3 = w + 2 * ND;
  const float* ctxB = ctx + ((size_t)b * NTC + t0) * ND;
  const float* qryB = qry + (size_t)b * NTQ * ND;

  float Sacc[4][16];
  float s1acc[4];
  #pragma unroll
  for (int r = 0; r < 4; ++r) {
    s1acc[r] = 0.f;
    #pragma unroll
    for (int j = 0; j < 16; ++j) Sacc[r][j] = 0.f;
  }

  // ---------------- Phase 1: S accumulation over d-chunks ----------------
  for (int dc = 0; dc < ND; dc += 64) {
    __syncthreads();
    #pragma unroll
    for (int k = 0; k < 16; ++k) {          // stage query chunk (raw)
      int f = tid + k * 256;                // 0..4095 float4s
      int q = f >> 4, g = f & 15;
      float4 v = *(const float4*)(qryB + (size_t)q * ND + dc + g * 4);
      *(float4*)(sQ + q * 68 + g * 4) = v;
    }
    #pragma unroll
    for (int k = 0; k < 4; ++k) {           // stage context tile chunk (raw)
      int f = tid + k * 256;
      int r = f >> 4, g = f & 15;
      float4 v = *(const float4*)(ctxB + (size_t)r * ND + dc + g * 4);
      *(float4*)(sC + r * 68 + g * 4) = v;
    }
    __syncthreads();
    for (int dd = 0; dd < 64; dd += 4) {
      float4 w1v = *(const float4*)(w1 + dc + dd);
      float4 w3v = *(const float4*)(w3 + dc + dd);
      float4 c3[4];
      #pragma unroll
      for (int r = 0; r < 4; ++r) {
        float4 c = *(const float4*)(sC + (4 * tt + r) * 68 + dd);
        s1acc[r] += c.x * w1v.x + c.y * w1v.y + c.z * w1v.z + c.w * w1v.w;
        c3[r] = make_float4(c.x * w3v.x, c.y * w3v.y, c.z * w3v.z, c.w * w3v.w);
      }
      #pragma unroll
      for (int j = 0; j < 16; ++j) {
        float4 qv = *(const float4*)(sQ + (tq + 16 * j) * 68 + dd);
        #pragma unroll
        for (int r = 0; r < 4; ++r) {
          Sacc[r][j] += c3[r].x * qv.x + c3[r].y * qv.y + c3[r].z * qv.z + c3[r].w * qv.w;
        }
      }
    }
  }

  // ---------------- softmax over q (row-wise) ----------------
  float q2v[16];
  #pragma unroll
  for (int j = 0; j < 16; ++j) q2v[j] = q2_ws[b * NTQ + tq + 16 * j];
  #pragma unroll
  for (int r = 0; r < 4; ++r) {
    #pragma unroll
    for (int j = 0; j < 16; ++j) Sacc[r][j] += s1acc[r] + q2v[j];
  }

  float mrow[4];
  #pragma unroll
  for (int r = 0; r < 4; ++r) {
    float mx = Sacc[r][0];
    #pragma unroll
    for (int j = 1; j < 16; ++j) mx = fmaxf(mx, Sacc[r][j]);
    #pragma unroll
    for (int s = 1; s < 16; s <<= 1) mx = fmaxf(mx, __shfl_xor(mx, s));
    mrow[r] = mx;
    float z = 0.f;
    #pragma unroll
    for (int j = 0; j < 16; ++j) { Sacc[r][j] = __expf(Sacc[r][j] - mx); z += Sacc[r][j]; }
    #pragma unroll
    for (int s = 1; s < 16; s <<= 1) z += __shfl_xor(z, s);
    float inv = 1.0f / z;
    #pragma unroll
    for (int j = 0; j < 16; ++j) sP[(4 * tt + r) * 260 + tq + 16 * j] = Sacc[r][j] * inv;
  }
  if (tq == 0) {
    #pragma unroll
    for (int r = 0; r < 4; ++r) m_ws[b * NTC + t0 + 4 * tt + r] = mrow[r];
  }

  // ---------------- Phase 2: U = P @ Q, write U and C*U ----------------
  for (int dc = 0; dc < ND; dc += 64) {
    __syncthreads();
    #pragma unroll
    for (int k = 0; k < 16; ++k) {          // restage query chunk
      int f = tid + k * 256;
      int q = f >> 4, g = f & 15;
      float4 v = *(const float4*)(qryB + (size_t)q * ND + dc + g * 4);
      *(float4*)(sQ + q * 68 + g * 4) = v;
    }
    __syncthreads();
    float Uacc[4][4];
    #pragma unroll
    for (int r = 0; r < 4; ++r)
      #pragma unroll
      for (int c = 0; c < 4; ++c) Uacc[r][c] = 0.f;

    for (int q = 0; q < NTQ; q += 4) {
      float4 pv[4];
      #pragma unroll
      for (int r = 0; r < 4; ++r) pv[r] = *(const float4*)(sP + (4 * tt + r) * 260 + q);
      #pragma unroll
      for (int qq = 0; qq < 4; ++qq) {
        float4 qv = *(const float4*)(sQ + (q + qq) * 68 + tq * 4);
        #pragma unroll
        for (int r = 0; r < 4; ++r) {
          float p = ((float*)&pv[r])[qq];
          Uacc[r][0] += p * qv.x;
          Uacc[r][1] += p * qv.y;
          Uacc[r][2] += p * qv.z;
          Uacc[r][3] += p * qv.w;
        }
      }
    }
    #pragma unroll
    for (int r = 0; r < 4; ++r) {
      int trow = 4 * tt + r;
      size_t gbase = ((size_t)b * NTC + t0 + trow) * 1024;
      float4 u = make_float4(Uacc[r][0], Uacc[r][1], Uacc[r][2], Uacc[r][3]);
      float4 c = *(const float4*)(ctxB + (size_t)trow * ND + dc + tq * 4);
      *(float4*)(G + gbase + 256 + dc + tq * 4) = u;
      *(float4*)(G + gbase + 512 + dc + tq * 4) =
          make_float4(c.x * u.x, c.y * u.y, c.z * u.z, c.w * u.w);
    }
  }
}

// K2: per (b, t-slice of 128): batch softmax over t of m, partial h
__global__ __launch_bounds__(256) void k2_bt(const float* __restrict__ ctx,
                                             const float* __restrict__ m_ws,
                                             float* __restrict__ h_part) {
  __shared__ __align__(16) float sM[NTC];
  __shared__ float red[32];
  int b = blockIdx.x >> 4;
  int slice = blockIdx.x & 15;
  int tid = threadIdx.x;

  float lm = -1e30f;
  #pragma unroll
  for (int k = 0; k < 8; ++k) {
    float v = m_ws[b * NTC + tid * 8 + k];
    sM[tid * 8 + k] = v;
    lm = fmaxf(lm, v);
  }
  #pragma unroll
  for (int s = 1; s < 64; s <<= 1) lm = fmaxf(lm, __shfl_xor(lm, s));
  if ((tid & 63) == 0) red[tid >> 6] = lm;
  __syncthreads();
  float M = fmaxf(fmaxf(red[0], red[1]), fmaxf(red[2], red[3]));
  float ls = 0.f;
  #pragma unroll
  for (int k = 0; k < 8; ++k) ls += __expf(sM[tid * 8 + k] - M);
  #pragma unroll
  for (int s = 1; s < 64; s <<= 1) ls += __shfl_xor(ls, s);
  if ((tid & 63) == 0) red[16 + (tid >> 6)] = ls;
  __syncthreads();
  float invZ = 1.0f / (red[16] + red[17] + red[18] + red[19]);

  int tbase = slice * 128;
  const float* cb = ctx + ((size_t)b * NTC + tbase) * ND + tid;
  float acc = 0.f;
  #pragma unroll 8
  for (int t = 0; t < 128; ++t) {
    float btv = __expf(sM[tbase + t] - M) * invZ;
    acc += btv * cb[(size_t)t * ND];
  }
  h_part[((size_t)b * 16 + slice) * ND + tid] = acc;
}

// K2b: h[b][d] = sum over 16 slices
__global__ __launch_bounds__(256) void k2b_hred(const float* __restrict__ h_part,
                                                float* __restrict__ h_ws) {
  int b = blockIdx.x;
  int d = threadIdx.x;
  float acc = 0.f;
  #pragma unroll
  for (int s = 0; s < 16; ++s) acc += h_part[((size_t)b * 16 + s) * ND + d];
  h_ws[b * ND + d] = acc;
}

// K3: G[...,0:256] = C ; G[...,768:1024] = C * h[b,:]
__global__ __launch_bounds__(256) void k3_epi(const float* __restrict__ ctx,
                                              const float* __restrict__ h_ws,
                                              float* __restrict__ G) {
  size_t f = (size_t)blockIdx.x * 256 + threadIdx.x;  // float4 id, 4,194,304 total
  size_t e = f * 4;
  int d = (int)(e & 255);
  size_t bt = e >> 8;
  int b = (int)(bt >> 11);
  float4 c = *(const float4*)(ctx + e);
  float4 h = *(const float4*)(h_ws + b * ND + d);
  *(float4*)(G + bt * 1024 + d) = c;
  *(float4*)(G + bt * 1024 + 768 + d) =
      make_float4(c.x * h.x, c.y * h.y, c.z * h.z, c.w * h.w);
}

extern "C" void kernel_launch(void* const* d_in, const int* in_sizes, int n_in,
                              void* d_out, int out_size, void* d_ws, size_t ws_size,
                              hipStream_t stream) {
  const float* ctx = (const float*)d_in[0];
  const float* qry = (const float*)d_in[1];
  const float* w   = (const float*)d_in[2];
  float* G  = (float*)d_out;
  float* ws = (float*)d_ws;
  float* q2_ws  = ws + Q2_OFF;
  float* m_ws   = ws + M_OFF;
  float* h_part = ws + HP_OFF;
  float* h_ws   = ws + H_OFF;

  k0_q2<<<NB, 256, 0, stream>>>(qry, w, q2_ws);
  k1_main<<<NB * (NTC / 64), 256, 0, stream>>>(ctx, qry, w, q2_ws, m_ws, G);
  k2_bt<<<NB * 16, 256, 0, stream>>>(ctx, m_ws, h_part);
  k2b_hred<<<NB, 256, 0, stream>>>(h_part, h_ws);
  k3_epi<<<16384, 256, 0, stream>>>(ctx, h_ws, G);
}

// Round 2
// 167.805 us; speedup vs baseline: 2.8854x; 2.8854x over previous
//
#include <hip/hip_runtime.h>

#define NB  32
#define NTC 2048
#define NTQ 256
#define ND  256

// ws layout (floats): m[32][2048] @0 ; h_part[32][16][256] @65536 ; h[32][256] @196608
#define M_OFF  0
#define HP_OFF 65536
#define H_OFF  196608

typedef __attribute__((ext_vector_type(8))) short short8v;
typedef __attribute__((ext_vector_type(4))) short short4v;
typedef __attribute__((ext_vector_type(4))) float float4v;

static __device__ inline short f2bf(float f) {
  union { float f; unsigned u; } v; v.f = f;
  unsigned r = v.u + 0x7FFFu + ((v.u >> 16) & 1u);
  return (short)(r >> 16);
}

// K1: per (b, 64-row tile).  Phase1: S = s1 + q2 + (C*w3)Q^T via MFMA (bf16).
// softmax in-register -> P bf16 to sPT (transposed). Phase2: U = P@Q via MFMA.
// Writes G[...,256:512]=U and G[...,512:768]=C*U (C kept fp32). m -> m_ws.
__global__ __launch_bounds__(256) void k1_main(const float* __restrict__ ctx,
                                               const float* __restrict__ qry,
                                               const float* __restrict__ w,
                                               float* __restrict__ m_ws,
                                               float* __restrict__ G) {
  __shared__ __align__(16) char smemA[40960];  // phase1: sQ(32KB)+sC(8KB); then sPT(40KB)
  __shared__ __align__(16) char smemB[32768];  // phase2: sQT
  __shared__ float q2s[256];

  short* sQ  = (short*)smemA;            // [256 q][64 d] bf16, octet-swizzled by q&7
  short* sC  = (short*)(smemA + 32768);  // [64 t][64 d]  bf16, octet-swizzled by t&7
  short* sPT = (short*)smemA;            // [4 waves][256 q][20]: P^T, 16 t + 4 pad
  short* sQT = (short*)smemB;            // [256 d][64 q] bf16, octet-swizzled by d&7

  const int tid  = threadIdx.x;
  const int wv   = tid >> 6;
  const int lane = tid & 63;
  const int g    = lane >> 4;
  const int li   = lane & 15;
  const int b    = blockIdx.x >> 5;
  const int t0   = (blockIdx.x & 31) << 6;

  const float* __restrict__ ctxB = ctx + ((size_t)b * NTC + t0) * ND;
  const float* __restrict__ qryB = qry + (size_t)b * NTQ * ND;
  const float* w1 = w;
  const float* w2 = w + ND;
  const float* w3 = w + 2 * ND;

  float4v acc[16];
  #pragma unroll
  for (int n = 0; n < 16; ++n) acc[n] = (float4v)0.f;
  float q2acc = 0.f, s1part = 0.f;

  // ================= Phase 1: S accumulation over 4 d-chunks =================
  for (int dc = 0; dc < ND; dc += 64) {
    __syncthreads();
    { // stage sQ: thread tid owns q-row = tid; also q2 partial
      const float* src = qryB + (size_t)tid * ND + dc;
      const float* w2p = w2 + dc;
      #pragma unroll
      for (int go = 0; go < 8; ++go) {
        float4 v0 = *(const float4*)(src + 8 * go);
        float4 v1 = *(const float4*)(src + 8 * go + 4);
        float4 u0 = *(const float4*)(w2p + 8 * go);
        float4 u1 = *(const float4*)(w2p + 8 * go + 4);
        q2acc += v0.x*u0.x + v0.y*u0.y + v0.z*u0.z + v0.w*u0.w
               + v1.x*u1.x + v1.y*u1.y + v1.z*u1.z + v1.w*u1.w;
        short8v pk;
        pk[0]=f2bf(v0.x); pk[1]=f2bf(v0.y); pk[2]=f2bf(v0.z); pk[3]=f2bf(v0.w);
        pk[4]=f2bf(v1.x); pk[5]=f2bf(v1.y); pk[6]=f2bf(v1.z); pk[7]=f2bf(v1.w);
        *(short8v*)(sQ + tid * 64 + ((go ^ (tid & 7)) << 3)) = pk;
      }
    }
    { // stage sC: wave-lane (row = 16w+li, 16 d at dc+16g); s1 partial; Cw3 bf16
      const int row = 16 * wv + li;
      const float* src = ctxB + (size_t)row * ND + dc + 16 * g;
      const float* w1p = w1 + dc + 16 * g;
      const float* w3p = w3 + dc + 16 * g;
      #pragma unroll
      for (int jj = 0; jj < 2; ++jj) {
        float4 c0 = *(const float4*)(src + 8 * jj);
        float4 c1 = *(const float4*)(src + 8 * jj + 4);
        float4 a0 = *(const float4*)(w1p + 8 * jj);
        float4 a1 = *(const float4*)(w1p + 8 * jj + 4);
        float4 b0 = *(const float4*)(w3p + 8 * jj);
        float4 b1 = *(const float4*)(w3p + 8 * jj + 4);
        s1part += c0.x*a0.x + c0.y*a0.y + c0.z*a0.z + c0.w*a0.w
                + c1.x*a1.x + c1.y*a1.y + c1.z*a1.z + c1.w*a1.w;
        short8v pk;
        pk[0]=f2bf(c0.x*b0.x); pk[1]=f2bf(c0.y*b0.y); pk[2]=f2bf(c0.z*b0.z); pk[3]=f2bf(c0.w*b0.w);
        pk[4]=f2bf(c1.x*b1.x); pk[5]=f2bf(c1.y*b1.y); pk[6]=f2bf(c1.z*b1.z); pk[7]=f2bf(c1.w*b1.w);
        const int go = 2 * g + jj;
        *(short8v*)(sC + row * 64 + ((go ^ (row & 7)) << 3)) = pk;
      }
    }
    if (dc == 192) q2s[tid] = q2acc;   // final accumulation done this chunk
    __syncthreads();
    // compute: 2 k-steps x 16 n-tiles
    #pragma unroll
    for (int ks = 0; ks < 2; ++ks) {
      const int row = 16 * wv + li;
      short8v a = *(short8v*)(sC + row * 64 + (((4*ks + g) ^ (li & 7)) << 3));
      #pragma unroll
      for (int n = 0; n < 16; ++n) {
        const int qr = 16 * n + li;
        short8v bb = *(short8v*)(sQ + qr * 64 + (((4*ks + g) ^ (li & 7)) << 3));
        acc[n] = __builtin_amdgcn_mfma_f32_16x16x32_bf16(a, bb, acc[n], 0, 0, 0);
      }
    }
  }

  // ================= softmax over q (rows 16w+4g+r, cols li+16n) =================
  s1part += __shfl_xor(s1part, 16);
  s1part += __shfl_xor(s1part, 32);
  float s1r[4];
  #pragma unroll
  for (int r = 0; r < 4; ++r) s1r[r] = __shfl(s1part, 4 * g + r);

  float q2v[16];
  #pragma unroll
  for (int n = 0; n < 16; ++n) q2v[n] = q2s[16 * n + li];

  #pragma unroll
  for (int n = 0; n < 16; ++n)
    #pragma unroll
    for (int r = 0; r < 4; ++r) acc[n][r] += s1r[r] + q2v[n];

  float mx[4], inv[4];
  #pragma unroll
  for (int r = 0; r < 4; ++r) {
    float m0 = acc[0][r];
    #pragma unroll
    for (int n = 1; n < 16; ++n) m0 = fmaxf(m0, acc[n][r]);
    m0 = fmaxf(m0, __shfl_xor(m0, 1));
    m0 = fmaxf(m0, __shfl_xor(m0, 2));
    m0 = fmaxf(m0, __shfl_xor(m0, 4));
    m0 = fmaxf(m0, __shfl_xor(m0, 8));
    mx[r] = m0;
  }
  if (li == 0) {
    #pragma unroll
    for (int r = 0; r < 4; ++r) m_ws[b * NTC + t0 + 16 * wv + 4 * g + r] = mx[r];
  }
  #pragma unroll
  for (int r = 0; r < 4; ++r) {
    float z = 0.f;
    #pragma unroll
    for (int n = 0; n < 16; ++n) { float e = __expf(acc[n][r] - mx[r]); acc[n][r] = e; z += e; }
    z += __shfl_xor(z, 1);
    z += __shfl_xor(z, 2);
    z += __shfl_xor(z, 4);
    z += __shfl_xor(z, 8);
    inv[r] = 1.0f / z;
  }

  __syncthreads();  // all waves done reading sQ/sC -> safe to overwrite with sPT
  short* sPTw = sPT + wv * 5120;
  #pragma unroll
  for (int n = 0; n < 16; ++n) {
    short4v pk;
    #pragma unroll
    for (int r = 0; r < 4; ++r) pk[r] = f2bf(acc[n][r] * inv[r]);
    *(short4v*)(sPTw + (16 * n + li) * 20 + 4 * g) = pk;  // P^T[q][t-local]
  }

  // ================= Phase 2: U = P @ Q over 4 q-chunks =================
  float4v acc2[16];
  #pragma unroll
  for (int n = 0; n < 16; ++n) acc2[n] = (float4v)0.f;

  for (int qc = 0; qc < 4; ++qc) {
    __syncthreads();
    { // stage sQT: thread tid owns d-row = tid; coalesced column reads of Q
      #pragma unroll
      for (int go = 0; go < 8; ++go) {
        short8v pk;
        #pragma unroll
        for (int e = 0; e < 8; ++e)
          pk[e] = f2bf(qryB[(size_t)(qc * 64 + 8 * go + e) * ND + tid]);
        *(short8v*)(sQT + tid * 64 + ((go ^ (tid & 7)) << 3)) = pk;
      }
    }
    __syncthreads();
    #pragma unroll
    for (int kl = 0; kl < 2; ++kl) {
      short8v a2;
      #pragma unroll
      for (int e = 0; e < 8; ++e)
        a2[e] = sPTw[(qc * 64 + 32 * kl + 8 * g + e) * 20 + li];
      #pragma unroll
      for (int n = 0; n < 16; ++n) {
        const int dr = 16 * n + li;
        short8v b2 = *(short8v*)(sQT + dr * 64 + (((4*kl + g) ^ (dr & 7)) << 3));
        acc2[n] = __builtin_amdgcn_mfma_f32_16x16x32_bf16(a2, b2, acc2[n], 0, 0, 0);
      }
    }
  }

  // ================= epilogue: G1 = U, G2 = C*U (C fp32) =================
  #pragma unroll
  for (int n = 0; n < 16; ++n) {
    #pragma unroll
    for (int r = 0; r < 4; ++r) {
      const int rloc = 16 * wv + 4 * g + r;
      const int d = 16 * n + li;
      const float u = acc2[n][r];
      const float c = ctxB[(size_t)rloc * ND + d];
      const size_t gb = ((size_t)b * NTC + t0 + rloc) * 1024;
      G[gb + 256 + d] = u;
      G[gb + 512 + d] = c * u;
    }
  }
}

// K2: per (b, t-slice of 128): batch softmax over t of m, partial h
__global__ __launch_bounds__(256) void k2_bt(const float* __restrict__ ctx,
                                             const float* __restrict__ m_ws,
                                             float* __restrict__ h_part) {
  __shared__ __align__(16) float sM[NTC];
  __shared__ float red[32];
  int b = blockIdx.x >> 4;
  int slice = blockIdx.x & 15;
  int tid = threadIdx.x;

  float lm = -1e30f;
  #pragma unroll
  for (int k = 0; k < 8; ++k) {
    float v = m_ws[b * NTC + tid * 8 + k];
    sM[tid * 8 + k] = v;
    lm = fmaxf(lm, v);
  }
  #pragma unroll
  for (int s = 1; s < 64; s <<= 1) lm = fmaxf(lm, __shfl_xor(lm, s));
  if ((tid & 63) == 0) red[tid >> 6] = lm;
  __syncthreads();
  float M = fmaxf(fmaxf(red[0], red[1]), fmaxf(red[2], red[3]));
  float ls = 0.f;
  #pragma unroll
  for (int k = 0; k < 8; ++k) ls += __expf(sM[tid * 8 + k] - M);
  #pragma unroll
  for (int s = 1; s < 64; s <<= 1) ls += __shfl_xor(ls, s);
  if ((tid & 63) == 0) red[16 + (tid >> 6)] = ls;
  __syncthreads();
  float invZ = 1.0f / (red[16] + red[17] + red[18] + red[19]);

  int tbase = slice * 128;
  const float* cb = ctx + ((size_t)b * NTC + tbase) * ND + tid;
  float acc = 0.f;
  #pragma unroll 8
  for (int t = 0; t < 128; ++t) {
    float btv = __expf(sM[tbase + t] - M) * invZ;
    acc += btv * cb[(size_t)t * ND];
  }
  h_part[((size_t)b * 16 + slice) * ND + tid] = acc;
}

// K2b: h[b][d] = sum over 16 slices
__global__ __launch_bounds__(256) void k2b_hred(const float* __restrict__ h_part,
                                                float* __restrict__ h_ws) {
  int b = blockIdx.x;
  int d = threadIdx.x;
  float acc = 0.f;
  #pragma unroll
  for (int s = 0; s < 16; ++s) acc += h_part[((size_t)b * 16 + s) * ND + d];
  h_ws[b * ND + d] = acc;
}

// K3: G[...,0:256] = C ; G[...,768:1024] = C * h[b,:]
__global__ __launch_bounds__(256) void k3_epi(const float* __restrict__ ctx,
                                              const float* __restrict__ h_ws,
                                              float* __restrict__ G) {
  size_t f = (size_t)blockIdx.x * 256 + threadIdx.x;
  size_t e = f * 4;
  int d = (int)(e & 255);
  size_t bt = e >> 8;
  int b = (int)(bt >> 11);
  float4 c = *(const float4*)(ctx + e);
  float4 h = *(const float4*)(h_ws + b * ND + d);
  *(float4*)(G + bt * 1024 + d) = c;
  *(float4*)(G + bt * 1024 + 768 + d) =
      make_float4(c.x * h.x, c.y * h.y, c.z * h.z, c.w * h.w);
}

extern "C" void kernel_launch(void* const* d_in, const int* in_sizes, int n_in,
                              void* d_out, int out_size, void* d_ws, size_t ws_size,
                              hipStream_t stream) {
  const float* ctx = (const float*)d_in[0];
  const float* qry = (const float*)d_in[1];
  const float* w   = (const float*)d_in[2];
  float* G  = (float*)d_out;
  float* ws = (float*)d_ws;
  float* m_ws   = ws + M_OFF;
  float* h_part = ws + HP_OFF;
  float* h_ws   = ws + H_OFF;

  k1_main<<<NB * (NTC / 64), 256, 0, stream>>>(ctx, qry, w, m_ws, G);
  k2_bt<<<NB * 16, 256, 0, stream>>>(ctx, m_ws, h_part);
  k2b_hred<<<NB, 256, 0, stream>>>(h_part, h_ws);
  k3_epi<<<16384, 256, 0, stream>>>(ctx, h_ws, G);
}